// Round 1
// baseline (341.788 us; speedup 1.0000x reference)
//
#include <hip/hip_runtime.h>
#include <math.h>

#define BATCH 8
#define NN 2048
#define FF 128

// ---------------------------------------------------------------------------
// Kernel 1: h = x @ W  (rows = B*N = 16384, K = F = 128, cols = F = 128)
// plus fused s_src[row] = h_row . a_src, s_dst[row] = h_row . a_dst
// grid: 1024 blocks x 128 threads; 16 rows per block; thread tile 4 rows x 4 cols
// ---------------------------------------------------------------------------
__global__ __launch_bounds__(128) void k_h(const float* __restrict__ x,
                                           const float* __restrict__ W,
                                           const float* __restrict__ a_src,
                                           const float* __restrict__ a_dst,
                                           float* __restrict__ h,
                                           float* __restrict__ s_src,
                                           float* __restrict__ s_dst) {
    // x rows staged transposed: xs[k*20 + r] (stride 20 words: 16B-aligned float4
    // reads at ty*4, and staging writes hit 32 banks 2-way = free)
    __shared__ float xs[128 * 20];
    const int t = threadIdx.x;
    const int row0 = blockIdx.x * 16;

    #pragma unroll
    for (int rr = 0; rr < 16; ++rr) {
        xs[t * 20 + rr] = x[(size_t)(row0 + rr) * FF + t];
    }
    __syncthreads();

    const int tx = t & 31;
    const int ty = t >> 5;  // 0..3 -> rows ty*4 .. ty*4+3

    float acc[4][4];
    #pragma unroll
    for (int r = 0; r < 4; ++r)
        #pragma unroll
        for (int c = 0; c < 4; ++c) acc[r][c] = 0.f;

    #pragma unroll 4
    for (int k = 0; k < FF; ++k) {
        const float4 xv = *reinterpret_cast<const float4*>(&xs[k * 20 + ty * 4]);
        const float w0 = W[k * FF + tx];
        const float w1 = W[k * FF + tx + 32];
        const float w2 = W[k * FF + tx + 64];
        const float w3 = W[k * FF + tx + 96];
        acc[0][0] = fmaf(xv.x, w0, acc[0][0]);
        acc[0][1] = fmaf(xv.x, w1, acc[0][1]);
        acc[0][2] = fmaf(xv.x, w2, acc[0][2]);
        acc[0][3] = fmaf(xv.x, w3, acc[0][3]);
        acc[1][0] = fmaf(xv.y, w0, acc[1][0]);
        acc[1][1] = fmaf(xv.y, w1, acc[1][1]);
        acc[1][2] = fmaf(xv.y, w2, acc[1][2]);
        acc[1][3] = fmaf(xv.y, w3, acc[1][3]);
        acc[2][0] = fmaf(xv.z, w0, acc[2][0]);
        acc[2][1] = fmaf(xv.z, w1, acc[2][1]);
        acc[2][2] = fmaf(xv.z, w2, acc[2][2]);
        acc[2][3] = fmaf(xv.z, w3, acc[2][3]);
        acc[3][0] = fmaf(xv.w, w0, acc[3][0]);
        acc[3][1] = fmaf(xv.w, w1, acc[3][1]);
        acc[3][2] = fmaf(xv.w, w2, acc[3][2]);
        acc[3][3] = fmaf(xv.w, w3, acc[3][3]);
    }

    const float as0 = a_src[tx], as1 = a_src[tx + 32], as2 = a_src[tx + 64], as3 = a_src[tx + 96];
    const float ad0 = a_dst[tx], ad1 = a_dst[tx + 32], ad2 = a_dst[tx + 64], ad3 = a_dst[tx + 96];

    #pragma unroll
    for (int r = 0; r < 4; ++r) {
        const int row = row0 + ty * 4 + r;
        float* hrow = h + (size_t)row * FF;
        hrow[tx]      = acc[r][0];
        hrow[tx + 32] = acc[r][1];
        hrow[tx + 64] = acc[r][2];
        hrow[tx + 96] = acc[r][3];
        float prow = acc[r][0] * as0 + acc[r][1] * as1 + acc[r][2] * as2 + acc[r][3] * as3;
        float drow = acc[r][0] * ad0 + acc[r][1] * ad1 + acc[r][2] * ad2 + acc[r][3] * ad3;
        // reduce over the 32 tx lanes (contiguous within the wave)
        #pragma unroll
        for (int off = 16; off >= 1; off >>= 1) {
            prow += __shfl_down(prow, off, 32);
            drow += __shfl_down(drow, off, 32);
        }
        if (tx == 0) {
            s_src[row] = prow;
            s_dst[row] = drow;
        }
    }
}

// ---------------------------------------------------------------------------
// Kernel 2: fused masked softmax + out = attn @ h
// grid: (N/16, B) blocks x 256 threads; block = 16 i-rows of one batch.
// Phase 1: m_r = max over masked j of s_dst[j] (lrelu monotone => max logit).
// Phase 2: j-tiles of 64: p into LDS, then register-tiled PV accumulate
//          (thread = 16 rows x 4 cols, j split 8 ways across thread groups).
// ---------------------------------------------------------------------------
__global__ __launch_bounds__(256, 4) void k_attn(const float* __restrict__ h,
                                                 const int* __restrict__ adj,
                                                 const float* __restrict__ s_src,
                                                 const float* __restrict__ s_dst,
                                                 float* __restrict__ out) {
    __shared__ float sd[NN];           // 8 KB  staged s_dst row for this batch
    __shared__ float ps[64 * 20];      // 5 KB  p[jj*20 + r], stride 20 (2-way writes, aligned b128 reads)
    __shared__ float si_s[16];
    __shared__ float m_s[16];
    __shared__ float l_s[16];
    __shared__ float outacc[16 * 128]; // 8 KB

    const int b = blockIdx.y;
    const int i0 = blockIdx.x * 16;
    const int t = threadIdx.x;

    for (int j = t; j < NN; j += 256) sd[j] = s_dst[(size_t)b * NN + j];
    if (t < 16) si_s[t] = s_src[(size_t)b * NN + i0 + t];
    __syncthreads();

    // ---- phase 1: masked max per row; mapping: 16 threads per row ----
    const int r0 = t >> 4;
    const int jl = t & 15;
    const int* __restrict__ adjrow = adj + (size_t)(i0 + r0) * NN;

    float mx = -INFINITY;
    for (int it = 0; it < NN / 16; ++it) {
        const int j = jl + (it << 4);
        if (adjrow[j] != 0) mx = fmaxf(mx, sd[j]);
    }
    #pragma unroll
    for (int off = 8; off >= 1; off >>= 1) mx = fmaxf(mx, __shfl_xor(mx, off, 16));
    if (jl == 0) m_s[r0] = mx;
    __syncthreads();

    const float m_r = m_s[r0];
    const float si_r = si_s[r0];
    float lpart = 0.f;

    // ---- phase 2 thread mapping for PV ----
    const int o4 = (t & 31) * 4;  // 4 output cols
    const int jq = t >> 5;        // 0..7: which 8-j slice of each 64-j tile

    float acc[16][4];
    #pragma unroll
    for (int r = 0; r < 16; ++r)
        #pragma unroll
        for (int c = 0; c < 4; ++c) acc[r][c] = 0.f;

    const float* __restrict__ hb = h + (size_t)b * NN * FF;

    for (int jt = 0; jt < NN; jt += 64) {
        // p generation: thread handles (r0, jl + 16q), q=0..3
        #pragma unroll
        for (int q = 0; q < 4; ++q) {
            const int jj = jl + (q << 4);
            const int j = jt + jj;
            float e = si_r + sd[j];
            e = (e >= 0.f) ? e : 0.2f * e;
            const float p = (adjrow[j] != 0) ? __expf(e - m_r) : 0.f;
            ps[jj * 20 + r0] = p;
            lpart += p;
        }
        __syncthreads();

        #pragma unroll
        for (int u = 0; u < 8; ++u) {
            const int jj = (jq << 3) + u;
            const float4 hv = *reinterpret_cast<const float4*>(&hb[(size_t)(jt + jj) * FF + o4]);
            const float4 p0 = *reinterpret_cast<const float4*>(&ps[jj * 20 + 0]);
            const float4 p1 = *reinterpret_cast<const float4*>(&ps[jj * 20 + 4]);
            const float4 p2 = *reinterpret_cast<const float4*>(&ps[jj * 20 + 8]);
            const float4 p3 = *reinterpret_cast<const float4*>(&ps[jj * 20 + 12]);
            const float pr[16] = {p0.x, p0.y, p0.z, p0.w, p1.x, p1.y, p1.z, p1.w,
                                  p2.x, p2.y, p2.z, p2.w, p3.x, p3.y, p3.z, p3.w};
            #pragma unroll
            for (int r = 0; r < 16; ++r) {
                acc[r][0] = fmaf(pr[r], hv.x, acc[r][0]);
                acc[r][1] = fmaf(pr[r], hv.y, acc[r][1]);
                acc[r][2] = fmaf(pr[r], hv.z, acc[r][2]);
                acc[r][3] = fmaf(pr[r], hv.w, acc[r][3]);
            }
        }
        __syncthreads();
    }

    // ---- row sums l ----
    #pragma unroll
    for (int off = 8; off >= 1; off >>= 1) lpart += __shfl_xor(lpart, off, 16);
    if (jl == 0) l_s[r0] = lpart;

    // ---- combine the 8 jq partial accumulators in LDS ----
    if (jq == 0) {
        #pragma unroll
        for (int r = 0; r < 16; ++r)
            *reinterpret_cast<float4*>(&outacc[r * 128 + o4]) =
                make_float4(acc[r][0], acc[r][1], acc[r][2], acc[r][3]);
    }
    for (int g = 1; g < 8; ++g) {
        __syncthreads();
        if (jq == g) {
            #pragma unroll
            for (int r = 0; r < 16; ++r) {
                float4 v = *reinterpret_cast<const float4*>(&outacc[r * 128 + o4]);
                v.x += acc[r][0]; v.y += acc[r][1]; v.z += acc[r][2]; v.w += acc[r][3];
                *reinterpret_cast<float4*>(&outacc[r * 128 + o4]) = v;
            }
        }
    }
    __syncthreads();

    // ---- normalize and write out ----
    const int oo = t & 127;
    const int rg = t >> 7;  // 0..1
    #pragma unroll
    for (int rr = 0; rr < 8; ++rr) {
        const int r = rg * 8 + rr;
        const float l = l_s[r];
        const float v = outacc[r * 128 + oo];
        out[((size_t)b * NN + i0 + r) * FF + oo] = (l > 0.f) ? v / l : 0.f;
    }
}

extern "C" void kernel_launch(void* const* d_in, const int* in_sizes, int n_in,
                              void* d_out, int out_size, void* d_ws, size_t ws_size,
                              hipStream_t stream) {
    const float* x     = (const float*)d_in[0];
    const int*   adj   = (const int*)d_in[1];
    const float* W     = (const float*)d_in[2];
    const float* a_src = (const float*)d_in[3];
    const float* a_dst = (const float*)d_in[4];
    float* out = (float*)d_out;

    float* h     = (float*)d_ws;                    // B*N*F floats = 8.4 MB
    float* s_src = h + (size_t)BATCH * NN * FF;     // B*N floats
    float* s_dst = s_src + (size_t)BATCH * NN;      // B*N floats

    k_h<<<BATCH * NN / 16, 128, 0, stream>>>(x, W, a_src, a_dst, h, s_src, s_dst);
    k_attn<<<dim3(NN / 16, BATCH), 256, 0, stream>>>(h, adj, s_src, s_dst, out);
}

// Round 2
// 244.777 us; speedup vs baseline: 1.3963x; 1.3963x over previous
//
#include <hip/hip_runtime.h>
#include <math.h>

#define BATCH 8
#define NN 2048
#define FF 128

// ---------------------------------------------------------------------------
// Kernel 1: h = x @ W  (rows = B*N = 16384, K = F = 128, cols = F = 128)
// plus fused s_src[row] = h_row . a_src, s_dst[row] = h_row . a_dst
// grid: 1024 blocks x 128 threads; 16 rows/block; thread = 4 rows x 4 cols
// (cols tx*4..tx*4+3 so W loads are one coalesced float4 per k)
// ---------------------------------------------------------------------------
__global__ __launch_bounds__(128) void k_h(const float* __restrict__ x,
                                           const float* __restrict__ W,
                                           const float* __restrict__ a_src,
                                           const float* __restrict__ a_dst,
                                           float* __restrict__ h,
                                           float* __restrict__ s_src,
                                           float* __restrict__ s_dst) {
    // x rows staged transposed: xs[k*20 + r] (stride 20: b128-aligned reads,
    // 2-way bank aliasing on writes = free)
    __shared__ float xs[128 * 20];
    const int t = threadIdx.x;
    const int row0 = blockIdx.x * 16;

    #pragma unroll
    for (int rr = 0; rr < 16; ++rr) {
        xs[t * 20 + rr] = x[(size_t)(row0 + rr) * FF + t];
    }
    __syncthreads();

    const int tx = t & 31;   // col group: cols tx*4 .. tx*4+3
    const int ty = t >> 5;   // row group: rows ty*4 .. ty*4+3

    float acc[4][4];
    #pragma unroll
    for (int r = 0; r < 4; ++r)
        #pragma unroll
        for (int c = 0; c < 4; ++c) acc[r][c] = 0.f;

    #pragma unroll 4
    for (int k = 0; k < FF; ++k) {
        const float4 xv = *reinterpret_cast<const float4*>(&xs[k * 20 + ty * 4]);
        const float4 wv = *reinterpret_cast<const float4*>(&W[k * FF + tx * 4]);
        acc[0][0] = fmaf(xv.x, wv.x, acc[0][0]);
        acc[0][1] = fmaf(xv.x, wv.y, acc[0][1]);
        acc[0][2] = fmaf(xv.x, wv.z, acc[0][2]);
        acc[0][3] = fmaf(xv.x, wv.w, acc[0][3]);
        acc[1][0] = fmaf(xv.y, wv.x, acc[1][0]);
        acc[1][1] = fmaf(xv.y, wv.y, acc[1][1]);
        acc[1][2] = fmaf(xv.y, wv.z, acc[1][2]);
        acc[1][3] = fmaf(xv.y, wv.w, acc[1][3]);
        acc[2][0] = fmaf(xv.z, wv.x, acc[2][0]);
        acc[2][1] = fmaf(xv.z, wv.y, acc[2][1]);
        acc[2][2] = fmaf(xv.z, wv.z, acc[2][2]);
        acc[2][3] = fmaf(xv.z, wv.w, acc[2][3]);
        acc[3][0] = fmaf(xv.w, wv.x, acc[3][0]);
        acc[3][1] = fmaf(xv.w, wv.y, acc[3][1]);
        acc[3][2] = fmaf(xv.w, wv.z, acc[3][2]);
        acc[3][3] = fmaf(xv.w, wv.w, acc[3][3]);
    }

    const float4 as = *reinterpret_cast<const float4*>(&a_src[tx * 4]);
    const float4 ad = *reinterpret_cast<const float4*>(&a_dst[tx * 4]);

    #pragma unroll
    for (int r = 0; r < 4; ++r) {
        const int row = row0 + ty * 4 + r;
        *reinterpret_cast<float4*>(&h[(size_t)row * FF + tx * 4]) =
            make_float4(acc[r][0], acc[r][1], acc[r][2], acc[r][3]);
        float prow = acc[r][0] * as.x + acc[r][1] * as.y + acc[r][2] * as.z + acc[r][3] * as.w;
        float drow = acc[r][0] * ad.x + acc[r][1] * ad.y + acc[r][2] * ad.z + acc[r][3] * ad.w;
        #pragma unroll
        for (int off = 16; off >= 1; off >>= 1) {
            prow += __shfl_down(prow, off, 32);
            drow += __shfl_down(drow, off, 32);
        }
        if (tx == 0) {
            s_src[row] = prow;
            s_dst[row] = drow;
        }
    }
}

// ---------------------------------------------------------------------------
// Kernel 2: fused masked softmax + out = attn @ h
// grid: (N/16, B) x 256 threads; block = 16 i-rows of one batch.
// Phase 1: per-row masked max logit (lrelu monotone => lrelu(si + max sd)).
// Phase 2: 64-j tiles: p into LDS, then PV with thread = 8 rows x 4 cols x
//          quarter-of-j (acc[8][4] = 32 VGPRs — NO SPILL, vs R1's 64+spill).
// ---------------------------------------------------------------------------
__global__ __launch_bounds__(256, 4) void k_attn(const float* __restrict__ h,
                                                 const int* __restrict__ adj,
                                                 const float* __restrict__ s_src,
                                                 const float* __restrict__ s_dst,
                                                 float* __restrict__ out) {
    __shared__ float sd[NN];           // 8 KB
    __shared__ float ps[64 * 20];      // 5 KB  p[jj*20 + r]; 80B stride => b128-aligned
    __shared__ float si_s[16];
    __shared__ float m_s[16];
    __shared__ float l_s[16];
    __shared__ float outacc[16 * 128]; // 8 KB

    const int b = blockIdx.y;
    const int i0 = blockIdx.x * 16;
    const int t = threadIdx.x;

    for (int j = t; j < NN; j += 256) sd[j] = s_dst[(size_t)b * NN + j];
    if (t < 16) si_s[t] = s_src[(size_t)b * NN + i0 + t];
    __syncthreads();

    // ---- phase 1: masked max per row; 16 threads per row ----
    const int r0 = t >> 4;
    const int jl = t & 15;
    const int* __restrict__ adjrow = adj + (size_t)(i0 + r0) * NN;

    float mx = -INFINITY;
    for (int it = 0; it < NN / 16; ++it) {
        const int j = jl + (it << 4);
        if (adjrow[j] != 0) mx = fmaxf(mx, sd[j]);
    }
    #pragma unroll
    for (int off = 8; off >= 1; off >>= 1) mx = fmaxf(mx, __shfl_xor(mx, off, 16));
    if (jl == 0) {
        float e = si_s[r0] + mx;             // max logit (pre-lrelu)
        m_s[r0] = (e >= 0.f) ? e : 0.2f * e; // lrelu monotone
    }
    __syncthreads();

    const float m_r = m_s[r0];
    const float si_r = si_s[r0];
    float lpart = 0.f;

    // ---- phase 2 thread mapping for PV ----
    const int cx = t & 31;        // col group: cols cx*4..cx*4+3
    const int rh = (t >> 5) & 1;  // row half: rows rh*8..rh*8+7
    const int jq = t >> 6;        // 0..3: 16-j slice of each 64-j tile

    float acc[8][4];
    #pragma unroll
    for (int r = 0; r < 8; ++r)
        #pragma unroll
        for (int c = 0; c < 4; ++c) acc[r][c] = 0.f;

    const float* __restrict__ hb = h + (size_t)b * NN * FF;

    for (int jt = 0; jt < NN; jt += 64) {
        // p generation: thread handles (r0, jl + 16q), q=0..3
        #pragma unroll
        for (int q = 0; q < 4; ++q) {
            const int jj = jl + (q << 4);
            const int j = jt + jj;
            float e = si_r + sd[j];
            e = (e >= 0.f) ? e : 0.2f * e;
            const float p = (adjrow[j] != 0) ? __expf(e - m_r) : 0.f;
            ps[jj * 20 + r0] = p;
            lpart += p;
        }
        __syncthreads();

        #pragma unroll 4
        for (int u = 0; u < 16; ++u) {
            const int jj = (jq << 4) + u;
            const float4 hv = *reinterpret_cast<const float4*>(&hb[(size_t)(jt + jj) * FF + cx * 4]);
            const float4 pa = *reinterpret_cast<const float4*>(&ps[jj * 20 + rh * 8]);
            const float4 pb = *reinterpret_cast<const float4*>(&ps[jj * 20 + rh * 8 + 4]);
            acc[0][0] = fmaf(pa.x, hv.x, acc[0][0]);
            acc[0][1] = fmaf(pa.x, hv.y, acc[0][1]);
            acc[0][2] = fmaf(pa.x, hv.z, acc[0][2]);
            acc[0][3] = fmaf(pa.x, hv.w, acc[0][3]);
            acc[1][0] = fmaf(pa.y, hv.x, acc[1][0]);
            acc[1][1] = fmaf(pa.y, hv.y, acc[1][1]);
            acc[1][2] = fmaf(pa.y, hv.z, acc[1][2]);
            acc[1][3] = fmaf(pa.y, hv.w, acc[1][3]);
            acc[2][0] = fmaf(pa.z, hv.x, acc[2][0]);
            acc[2][1] = fmaf(pa.z, hv.y, acc[2][1]);
            acc[2][2] = fmaf(pa.z, hv.z, acc[2][2]);
            acc[2][3] = fmaf(pa.z, hv.w, acc[2][3]);
            acc[3][0] = fmaf(pa.w, hv.x, acc[3][0]);
            acc[3][1] = fmaf(pa.w, hv.y, acc[3][1]);
            acc[3][2] = fmaf(pa.w, hv.z, acc[3][2]);
            acc[3][3] = fmaf(pa.w, hv.w, acc[3][3]);
            acc[4][0] = fmaf(pb.x, hv.x, acc[4][0]);
            acc[4][1] = fmaf(pb.x, hv.y, acc[4][1]);
            acc[4][2] = fmaf(pb.x, hv.z, acc[4][2]);
            acc[4][3] = fmaf(pb.x, hv.w, acc[4][3]);
            acc[5][0] = fmaf(pb.y, hv.x, acc[5][0]);
            acc[5][1] = fmaf(pb.y, hv.y, acc[5][1]);
            acc[5][2] = fmaf(pb.y, hv.z, acc[5][2]);
            acc[5][3] = fmaf(pb.y, hv.w, acc[5][3]);
            acc[6][0] = fmaf(pb.z, hv.x, acc[6][0]);
            acc[6][1] = fmaf(pb.z, hv.y, acc[6][1]);
            acc[6][2] = fmaf(pb.z, hv.z, acc[6][2]);
            acc[6][3] = fmaf(pb.z, hv.w, acc[6][3]);
            acc[7][0] = fmaf(pb.w, hv.x, acc[7][0]);
            acc[7][1] = fmaf(pb.w, hv.y, acc[7][1]);
            acc[7][2] = fmaf(pb.w, hv.z, acc[7][2]);
            acc[7][3] = fmaf(pb.w, hv.w, acc[7][3]);
        }
        __syncthreads();
    }

    // ---- row sums l ----
    #pragma unroll
    for (int off = 8; off >= 1; off >>= 1) lpart += __shfl_xor(lpart, off, 16);
    if (jl == 0) l_s[r0] = lpart;

    // ---- combine the 4 jq partial accumulators in LDS ----
    if (jq == 0) {
        #pragma unroll
        for (int r = 0; r < 8; ++r)
            *reinterpret_cast<float4*>(&outacc[(rh * 8 + r) * 128 + cx * 4]) =
                make_float4(acc[r][0], acc[r][1], acc[r][2], acc[r][3]);
    }
    #pragma unroll
    for (int g = 1; g < 4; ++g) {
        __syncthreads();
        if (jq == g) {
            #pragma unroll
            for (int r = 0; r < 8; ++r) {
                float4 v = *reinterpret_cast<const float4*>(&outacc[(rh * 8 + r) * 128 + cx * 4]);
                v.x += acc[r][0]; v.y += acc[r][1]; v.z += acc[r][2]; v.w += acc[r][3];
                *reinterpret_cast<float4*>(&outacc[(rh * 8 + r) * 128 + cx * 4]) = v;
            }
        }
    }
    __syncthreads();

    // ---- normalize and write out ----
    const int oo = t & 127;
    const int rg = t >> 7;  // 0..1
    #pragma unroll
    for (int rr = 0; rr < 8; ++rr) {
        const int r = rg * 8 + rr;
        const float l = l_s[r];
        const float v = outacc[r * 128 + oo];
        out[((size_t)b * NN + i0 + r) * FF + oo] = (l > 0.f) ? v / l : 0.f;
    }
}

extern "C" void kernel_launch(void* const* d_in, const int* in_sizes, int n_in,
                              void* d_out, int out_size, void* d_ws, size_t ws_size,
                              hipStream_t stream) {
    const float* x     = (const float*)d_in[0];
    const int*   adj   = (const int*)d_in[1];
    const float* W     = (const float*)d_in[2];
    const float* a_src = (const float*)d_in[3];
    const float* a_dst = (const float*)d_in[4];
    float* out = (float*)d_out;

    float* h     = (float*)d_ws;                    // B*N*F floats = 8.4 MB
    float* s_src = h + (size_t)BATCH * NN * FF;     // B*N floats
    float* s_dst = s_src + (size_t)BATCH * NN;      // B*N floats

    k_h<<<BATCH * NN / 16, 128, 0, stream>>>(x, W, a_src, a_dst, h, s_src, s_dst);
    k_attn<<<dim3(NN / 16, BATCH), 256, 0, stream>>>(h, adj, s_src, s_dst, out);
}

// Round 3
// 131.901 us; speedup vs baseline: 2.5912x; 1.8558x over previous
//
#include <hip/hip_runtime.h>
#include <math.h>

#define BATCH 8
#define NN 2048
#define FF 128

typedef __attribute__((ext_vector_type(8))) short short8;   // 8 bf16 (4 VGPRs)
typedef __attribute__((ext_vector_type(4))) float f32x4;    // MFMA accumulator

__device__ __forceinline__ unsigned short bf16_rne(float f) {
    unsigned int u = __float_as_uint(f);
    unsigned int r = u + 0x7fffu + ((u >> 16) & 1u);
    return (unsigned short)(r >> 16);
}

// ---------------------------------------------------------------------------
// k_pack: adj int32 [N][N] -> bitmask u32 [N][N/32]
// ---------------------------------------------------------------------------
__global__ __launch_bounds__(256) void k_pack(const int* __restrict__ adj,
                                              unsigned* __restrict__ adjb) {
    const int tg = blockIdx.x * 256 + threadIdx.x;   // 0 .. 2048*64-1
    const int i = tg >> 6, w = tg & 63;
    const int* p = adj + (size_t)i * NN + w * 32;
    unsigned m = 0;
    #pragma unroll
    for (int q = 0; q < 8; ++q) {
        const int4 v = *reinterpret_cast<const int4*>(p + q * 4);
        if (v.x) m |= 1u << (q * 4 + 0);
        if (v.y) m |= 1u << (q * 4 + 1);
        if (v.z) m |= 1u << (q * 4 + 2);
        if (v.w) m |= 1u << (q * 4 + 3);
    }
    adjb[tg] = m;
}

// ---------------------------------------------------------------------------
// k_h: h = x@W, emitted as bf16 hi/lo planes in MFMA-B-fragment-ready layout
//   plane[b][ntile(8)][jg(256)][n(16)][u(8)]  where j = jg*8+u, col = ntile*16+n
// plus s_src/s_dst fused. 512 blocks x 256 thr; 32 rows/block; W staged in LDS
// by 32-k chunks (no global loads in inner loop).
// ---------------------------------------------------------------------------
__global__ __launch_bounds__(256) void k_h(const float* __restrict__ x,
                                           const float* __restrict__ W,
                                           const float* __restrict__ a_src,
                                           const float* __restrict__ a_dst,
                                           unsigned short* __restrict__ hF_hi,
                                           unsigned short* __restrict__ hF_lo,
                                           float* __restrict__ s_src,
                                           float* __restrict__ s_dst) {
    __shared__ float xs[128 * 36];   // 18KB  xs[k*36 + r], r = 0..31
    __shared__ float Ws[32 * 128];   // 16KB

    const int t = threadIdx.x;
    const int row0 = blockIdx.x * 32;       // global row (= b*2048 + j0)
    const int b = row0 >> 11;
    const int j0 = row0 & 2047;

    // stage x transposed (protected by first barrier in kc loop)
    #pragma unroll
    for (int it = 0; it < 16; ++it) {
        const int idx = it * 256 + t;
        const int kk = idx & 127, r = idx >> 7;
        xs[kk * 36 + r] = x[(size_t)(row0 + r) * FF + kk];
    }

    const int tx = t & 31;   // cols tx*4 .. +3
    const int ty = t >> 5;   // rows ty*4 .. +3  (ty 0..7)

    float acc[4][4];
    #pragma unroll
    for (int r = 0; r < 4; ++r)
        #pragma unroll
        for (int c = 0; c < 4; ++c) acc[r][c] = 0.f;

    for (int kc = 0; kc < 4; ++kc) {
        __syncthreads();
        #pragma unroll
        for (int it = 0; it < 4; ++it) {
            const int idx = it * 1024 + t * 4;
            *reinterpret_cast<float4*>(&Ws[idx]) =
                *reinterpret_cast<const float4*>(&W[kc * 4096 + idx]);
        }
        __syncthreads();
        #pragma unroll 8
        for (int k2 = 0; k2 < 32; ++k2) {
            const int k = kc * 32 + k2;
            const float4 xv = *reinterpret_cast<const float4*>(&xs[k * 36 + ty * 4]);
            const float4 wv = *reinterpret_cast<const float4*>(&Ws[k2 * 128 + tx * 4]);
            acc[0][0] = fmaf(xv.x, wv.x, acc[0][0]);
            acc[0][1] = fmaf(xv.x, wv.y, acc[0][1]);
            acc[0][2] = fmaf(xv.x, wv.z, acc[0][2]);
            acc[0][3] = fmaf(xv.x, wv.w, acc[0][3]);
            acc[1][0] = fmaf(xv.y, wv.x, acc[1][0]);
            acc[1][1] = fmaf(xv.y, wv.y, acc[1][1]);
            acc[1][2] = fmaf(xv.y, wv.z, acc[1][2]);
            acc[1][3] = fmaf(xv.y, wv.w, acc[1][3]);
            acc[2][0] = fmaf(xv.z, wv.x, acc[2][0]);
            acc[2][1] = fmaf(xv.z, wv.y, acc[2][1]);
            acc[2][2] = fmaf(xv.z, wv.z, acc[2][2]);
            acc[2][3] = fmaf(xv.z, wv.w, acc[2][3]);
            acc[3][0] = fmaf(xv.w, wv.x, acc[3][0]);
            acc[3][1] = fmaf(xv.w, wv.y, acc[3][1]);
            acc[3][2] = fmaf(xv.w, wv.z, acc[3][2]);
            acc[3][3] = fmaf(xv.w, wv.w, acc[3][3]);
        }
    }

    // ---- emit bf16 hi/lo planes in B-frag-ready layout ----
    const int jl = j0 + ty * 4;          // local j of this thread's first row
    const int jg = jl >> 3;
    const int u0 = jl & 7;               // 0 or 4 -> 8B-aligned ushort4 stores
    #pragma unroll
    for (int c = 0; c < 4; ++c) {
        const int col = tx * 4 + c;
        const int ntg = col >> 4, n = col & 15;
        const size_t e = (size_t)b * 262144 + ntg * 32768 + jg * 128 + n * 8 + u0;
        ushort4 hv, lv;
        {
            float f, hf;
            f = acc[0][c]; hv.x = bf16_rne(f); hf = __uint_as_float((unsigned)hv.x << 16); lv.x = bf16_rne(f - hf);
            f = acc[1][c]; hv.y = bf16_rne(f); hf = __uint_as_float((unsigned)hv.y << 16); lv.y = bf16_rne(f - hf);
            f = acc[2][c]; hv.z = bf16_rne(f); hf = __uint_as_float((unsigned)hv.z << 16); lv.z = bf16_rne(f - hf);
            f = acc[3][c]; hv.w = bf16_rne(f); hf = __uint_as_float((unsigned)hv.w << 16); lv.w = bf16_rne(f - hf);
        }
        *reinterpret_cast<ushort4*>(&hF_hi[e]) = hv;
        *reinterpret_cast<ushort4*>(&hF_lo[e]) = lv;
    }

    // ---- fused s_src / s_dst ----
    const float4 as4 = *reinterpret_cast<const float4*>(&a_src[tx * 4]);
    const float4 ad4 = *reinterpret_cast<const float4*>(&a_dst[tx * 4]);
    #pragma unroll
    for (int r = 0; r < 4; ++r) {
        float prow = acc[r][0] * as4.x + acc[r][1] * as4.y + acc[r][2] * as4.z + acc[r][3] * as4.w;
        float drow = acc[r][0] * ad4.x + acc[r][1] * ad4.y + acc[r][2] * ad4.z + acc[r][3] * ad4.w;
        #pragma unroll
        for (int off = 16; off >= 1; off >>= 1) {
            prow += __shfl_down(prow, off, 32);
            drow += __shfl_down(drow, off, 32);
        }
        if (tx == 0) {
            s_src[row0 + ty * 4 + r] = prow;
            s_dst[row0 + ty * 4 + r] = drow;
        }
    }
}

// ---------------------------------------------------------------------------
// k_attn: fused masked softmax (no max pass; exp directly, shift-invariant)
// + PV via 16x16x32 bf16 MFMA with bf16x2 split (3 MFMAs per tile pair).
// grid (32, 8) = 256 blocks (1/CU), 512 thr = 8 waves.
// block = 64 i-rows x 128 cols; wave = 16 rows (mtile) x 64 cols (4 ntiles).
// j-loop: 64 tiles of 32; p generated into double-buffered LDS (1 barrier/tile).
// ---------------------------------------------------------------------------
__global__ __launch_bounds__(512) void k_attn(const unsigned short* __restrict__ hF_hi,
                                              const unsigned short* __restrict__ hF_lo,
                                              const unsigned* __restrict__ adjb,
                                              const float* __restrict__ s_src,
                                              const float* __restrict__ s_dst,
                                              float* __restrict__ out) {
    __shared__ float sd[NN];                     // 8KB
    __shared__ unsigned am[64 * 64];             // 16KB block's adj bitmask rows
    __shared__ unsigned short pA_hi[2][64 * 40]; // 10KB  p rows, stride 40 (bank-spread)
    __shared__ unsigned short pA_lo[2][64 * 40]; // 10KB
    __shared__ float si_s[64];
    __shared__ float linv[64];

    const int t = threadIdx.x;
    const int b = blockIdx.y;
    const int i0 = blockIdx.x * 64;

    // ---- stage sd, adj bitmask, si ----
    *reinterpret_cast<float4*>(&sd[t * 4]) =
        *reinterpret_cast<const float4*>(&s_dst[(size_t)b * NN + t * 4]);
    {
        const unsigned* ag = adjb + (size_t)i0 * 64;
        *reinterpret_cast<uint4*>(&am[t * 8]) = *reinterpret_cast<const uint4*>(&ag[t * 8]);
        *reinterpret_cast<uint4*>(&am[t * 8 + 4]) = *reinterpret_cast<const uint4*>(&ag[t * 8 + 4]);
    }
    if (t < 64) si_s[t] = s_src[(size_t)b * NN + i0 + t];
    __syncthreads();

    // ---- ids ----
    const int pi = t >> 3;          // p-gen row 0..63
    const int jq = t & 7;           // p-gen j-slot: j = jq*4 + 0..3
    const float si = si_s[pi];

    const int w = t >> 6;           // wave 0..7
    const int lane = t & 63;
    const int mt = w >> 1;          // mtile 0..3 (rows mt*16..+15)
    const int ch = w & 1;           // col half
    const int nl = lane & 15;       // n (B) / m (A) index
    const int quad = lane >> 4;     // 0..3

    const unsigned short* Bh = hF_hi + (size_t)b * 262144;
    const unsigned short* Bl = hF_lo + (size_t)b * 262144;
    // per-ntile base offsets; per tile add jt*16
    int bofs[4];
    #pragma unroll
    for (int nt = 0; nt < 4; ++nt)
        bofs[nt] = (ch * 4 + nt) * 32768 + quad * 128 + nl * 8;

    const int aofs = (mt * 16 + nl) * 40 + quad * 8;  // A-frag ushort offset
    const int pw = pi * 40 + jq * 4;                  // p-gen write offset

    f32x4 acc0 = {0.f, 0.f, 0.f, 0.f};
    f32x4 acc1 = {0.f, 0.f, 0.f, 0.f};
    f32x4 acc2 = {0.f, 0.f, 0.f, 0.f};
    f32x4 acc3 = {0.f, 0.f, 0.f, 0.f};
    float lpart = 0.f;

    for (int tt = 0; tt < 64; ++tt) {
        const int jt = tt * 32;
        const int buf = tt & 1;
        const int jofs = jt * 16;

        // ---- B-frag loads (issued early; consumed after the barrier) ----
        const short8 bh0 = *reinterpret_cast<const short8*>(Bh + bofs[0] + jofs);
        const short8 bh1 = *reinterpret_cast<const short8*>(Bh + bofs[1] + jofs);
        const short8 bh2 = *reinterpret_cast<const short8*>(Bh + bofs[2] + jofs);
        const short8 bh3 = *reinterpret_cast<const short8*>(Bh + bofs[3] + jofs);
        const short8 bl0 = *reinterpret_cast<const short8*>(Bl + bofs[0] + jofs);
        const short8 bl1 = *reinterpret_cast<const short8*>(Bl + bofs[1] + jofs);
        const short8 bl2 = *reinterpret_cast<const short8*>(Bl + bofs[2] + jofs);
        const short8 bl3 = *reinterpret_cast<const short8*>(Bl + bofs[3] + jofs);

        // ---- p-gen: 4 values for (row pi, j = jt + jq*4 + 0..3) ----
        {
            const unsigned m32 = am[pi * 64 + tt];
            const float4 sj = *reinterpret_cast<const float4*>(&sd[jt + jq * 4]);
            float p[4];
            const float ej[4] = {sj.x, sj.y, sj.z, sj.w};
            #pragma unroll
            for (int kk = 0; kk < 4; ++kk) {
                float e = si + ej[kk];
                e = (e >= 0.f) ? e : 0.2f * e;
                const float pe = __expf(e);
                p[kk] = ((m32 >> (jq * 4 + kk)) & 1u) ? pe : 0.f;
            }
            lpart += p[0] + p[1] + p[2] + p[3];
            ushort4 phv, plv;
            float hf;
            phv.x = bf16_rne(p[0]); hf = __uint_as_float((unsigned)phv.x << 16); plv.x = bf16_rne(p[0] - hf);
            phv.y = bf16_rne(p[1]); hf = __uint_as_float((unsigned)phv.y << 16); plv.y = bf16_rne(p[1] - hf);
            phv.z = bf16_rne(p[2]); hf = __uint_as_float((unsigned)phv.z << 16); plv.z = bf16_rne(p[2] - hf);
            phv.w = bf16_rne(p[3]); hf = __uint_as_float((unsigned)phv.w << 16); plv.w = bf16_rne(p[3] - hf);
            *reinterpret_cast<ushort4*>(&pA_hi[buf][pw]) = phv;
            *reinterpret_cast<ushort4*>(&pA_lo[buf][pw]) = plv;
        }

        __syncthreads();

        // ---- A-frags from LDS ----
        const short8 ah = *reinterpret_cast<const short8*>(&pA_hi[buf][aofs]);
        const short8 al = *reinterpret_cast<const short8*>(&pA_lo[buf][aofs]);

        // ---- MFMAs: hi*hi + lo*hi + hi*lo per ntile ----
        acc0 = __builtin_amdgcn_mfma_f32_16x16x32_bf16(ah, bh0, acc0, 0, 0, 0);
        acc1 = __builtin_amdgcn_mfma_f32_16x16x32_bf16(ah, bh1, acc1, 0, 0, 0);
        acc2 = __builtin_amdgcn_mfma_f32_16x16x32_bf16(ah, bh2, acc2, 0, 0, 0);
        acc3 = __builtin_amdgcn_mfma_f32_16x16x32_bf16(ah, bh3, acc3, 0, 0, 0);
        acc0 = __builtin_amdgcn_mfma_f32_16x16x32_bf16(al, bh0, acc0, 0, 0, 0);
        acc1 = __builtin_amdgcn_mfma_f32_16x16x32_bf16(al, bh1, acc1, 0, 0, 0);
        acc2 = __builtin_amdgcn_mfma_f32_16x16x32_bf16(al, bh2, acc2, 0, 0, 0);
        acc3 = __builtin_amdgcn_mfma_f32_16x16x32_bf16(al, bh3, acc3, 0, 0, 0);
        acc0 = __builtin_amdgcn_mfma_f32_16x16x32_bf16(ah, bl0, acc0, 0, 0, 0);
        acc1 = __builtin_amdgcn_mfma_f32_16x16x32_bf16(ah, bl1, acc1, 0, 0, 0);
        acc2 = __builtin_amdgcn_mfma_f32_16x16x32_bf16(ah, bl2, acc2, 0, 0, 0);
        acc3 = __builtin_amdgcn_mfma_f32_16x16x32_bf16(ah, bl3, acc3, 0, 0, 0);
    }

    // ---- row sums -> 1/l ----
    lpart += __shfl_xor(lpart, 1, 8);
    lpart += __shfl_xor(lpart, 2, 8);
    lpart += __shfl_xor(lpart, 4, 8);
    __syncthreads();   // all reads of pA done; safe to reuse nothing, just order linv
    if (jq == 0) linv[pi] = (lpart > 0.f) ? 1.0f / lpart : 0.f;
    __syncthreads();

    // ---- epilogue: C/D layout col=lane&15, row=quad*4+reg ----
    const int col0 = ch * 64 + nl;
    const f32x4 av[4] = {acc0, acc1, acc2, acc3};
    #pragma unroll
    for (int nt = 0; nt < 4; ++nt) {
        #pragma unroll
        for (int r = 0; r < 4; ++r) {
            const int lrow = mt * 16 + quad * 4 + r;
            const float inv = linv[lrow];
            out[((size_t)b * NN + i0 + lrow) * FF + col0 + nt * 16] = av[nt][r] * inv;
        }
    }
}

extern "C" void kernel_launch(void* const* d_in, const int* in_sizes, int n_in,
                              void* d_out, int out_size, void* d_ws, size_t ws_size,
                              hipStream_t stream) {
    const float* x     = (const float*)d_in[0];
    const int*   adj   = (const int*)d_in[1];
    const float* W     = (const float*)d_in[2];
    const float* a_src = (const float*)d_in[3];
    const float* a_dst = (const float*)d_in[4];
    float* out = (float*)d_out;

    unsigned short* hF_hi = (unsigned short*)d_ws;        // 2M ushort = 4MB
    unsigned short* hF_lo = hF_hi + 2097152;              // 4MB
    float* s_src = (float*)(hF_lo + 2097152);             // 64KB
    float* s_dst = s_src + 16384;                         // 64KB
    unsigned* adjb = (unsigned*)(s_dst + 16384);          // 512KB

    k_pack<<<512, 256, 0, stream>>>(adj, adjb);
    k_h<<<512, 256, 0, stream>>>(x, W, a_src, a_dst, hF_hi, hF_lo, s_src, s_dst);
    k_attn<<<dim3(NN / 64, BATCH), 512, 0, stream>>>(hF_hi, hF_lo, adjb, s_src, s_dst, out);
}

// Round 5
// 131.504 us; speedup vs baseline: 2.5991x; 1.0030x over previous
//
#include <hip/hip_runtime.h>
#include <math.h>

#define BATCH 8
#define NN 2048
#define FF 128

typedef __attribute__((ext_vector_type(4))) float f32x4;
typedef _Float16 half8 __attribute__((ext_vector_type(8)));

__device__ __forceinline__ unsigned short h2u(_Float16 h) {
    return __builtin_bit_cast(unsigned short, h);
}

// split f -> fp16 hi + fp16 lo (residual), RNE
__device__ __forceinline__ void h_split(float f, unsigned short& hi, unsigned short& lo) {
    const _Float16 hh = (_Float16)f;
    hi = h2u(hh);
    lo = h2u((_Float16)(f - (float)hh));
}

// ---------------------------------------------------------------------------
// k_prep: blocks 0..127: adj -> transposed bitmask amT[jw(64)][i(2048)] via ballot.
//         block 128: W -> fp16 hi/lo B-fragment planes Wf[ks(4)][nt(8)][lane(64)][j(8)]
// ---------------------------------------------------------------------------
__global__ __launch_bounds__(512) void k_prep(const int* __restrict__ adj,
                                              const float* __restrict__ W,
                                              unsigned short* __restrict__ Wf_hi,
                                              unsigned short* __restrict__ Wf_lo,
                                              unsigned* __restrict__ amT) {
    const int t = threadIdx.x;
    if (blockIdx.x == 128) {
        #pragma unroll 4
        for (int e = 0; e < 32; ++e) {
            const int fi = e * 512 + t;
            const int j = fi & 7, lane = (fi >> 3) & 63, nt = (fi >> 9) & 7, ks = fi >> 12;
            const int k = ks * 32 + (lane >> 4) * 8 + j;
            const int col = nt * 16 + (lane & 15);
            unsigned short hh, hl;
            h_split(W[k * FF + col], hh, hl);
            Wf_hi[fi] = hh;
            Wf_lo[fi] = hl;
        }
    } else {
        const int w = t >> 6, lane = t & 63;
        const int row = blockIdx.x * 16 + w * 2;
        #pragma unroll
        for (int rr = 0; rr < 2; ++rr) {
            const int* __restrict__ ar = adj + (size_t)(row + rr) * NN;
            for (int seg = 0; seg < 32; ++seg) {
                const unsigned long long m = __ballot(ar[seg * 64 + lane] != 0);
                if (lane == 0)  amT[(size_t)(seg * 2) * NN + row + rr] = (unsigned)m;
                if (lane == 32) amT[(size_t)(seg * 2 + 1) * NN + row + rr] = (unsigned)(m >> 32);
            }
        }
    }
}

// ---------------------------------------------------------------------------
// k_h: h = x@W via fp16-split MFMA (xh*Wh + xl*Wh + xh*Wl), h emitted as ONE
// fp16 plane in k_attn's B-frag layout; epilogue computes s_src/s_dst and the
// factored exponentials Eg/E2g (from s_dst) and Sg/S2g (from s_src).
// grid 256 x 512: block = 64 rows x 128 cols; wave = 16 rows x 64 cols.
// ---------------------------------------------------------------------------
__global__ __launch_bounds__(512) void k_h(const float* __restrict__ x,
                                           const unsigned short* __restrict__ Wf_hi,
                                           const unsigned short* __restrict__ Wf_lo,
                                           const float* __restrict__ a_src,
                                           const float* __restrict__ a_dst,
                                           unsigned short* __restrict__ hF,
                                           float* __restrict__ Eg,  float* __restrict__ E2g,
                                           float* __restrict__ Sg,  float* __restrict__ S2g) {
    __shared__ float sred[2][64];
    __shared__ float dred[2][64];

    const int t = threadIdx.x;
    const int w = t >> 6, lane = t & 63;
    const int mt = w >> 1, ch = w & 1;
    const int nl = lane & 15, quad = lane >> 4;
    const int row0 = blockIdx.x * 64;
    const int b = row0 >> 11, jloc0 = row0 & 2047;
    const int gr = row0 + mt * 16 + nl;

    f32x4 acc[4] = {{0.f,0.f,0.f,0.f},{0.f,0.f,0.f,0.f},{0.f,0.f,0.f,0.f},{0.f,0.f,0.f,0.f}};

    #pragma unroll
    for (int ks = 0; ks < 4; ++ks) {
        const float4 xa = *reinterpret_cast<const float4*>(&x[(size_t)gr * FF + ks * 32 + quad * 8]);
        const float4 xb = *reinterpret_cast<const float4*>(&x[(size_t)gr * FF + ks * 32 + quad * 8 + 4]);
        const float xv[8] = {xa.x, xa.y, xa.z, xa.w, xb.x, xb.y, xb.z, xb.w};
        half8 ah, al;
        #pragma unroll
        for (int i = 0; i < 8; ++i) {
            const _Float16 hh = (_Float16)xv[i];
            ah[i] = hh;
            al[i] = (_Float16)(xv[i] - (float)hh);
        }
        #pragma unroll
        for (int nt = 0; nt < 4; ++nt) {
            const int gnt = ch * 4 + nt;
            const int bo = ((ks * 8 + gnt) * 64 + lane) * 8;
            const half8 bh = *reinterpret_cast<const half8*>(&Wf_hi[bo]);
            const half8 bl = *reinterpret_cast<const half8*>(&Wf_lo[bo]);
            acc[nt] = __builtin_amdgcn_mfma_f32_16x16x32_f16(ah, bh, acc[nt], 0, 0, 0);
            acc[nt] = __builtin_amdgcn_mfma_f32_16x16x32_f16(al, bh, acc[nt], 0, 0, 0);
            acc[nt] = __builtin_amdgcn_mfma_f32_16x16x32_f16(ah, bl, acc[nt], 0, 0, 0);
        }
    }

    // ---- h store: fp16 plane, B-frag layout [b][gnt][jg][n][u] ----
    const int jloc = jloc0 + mt * 16 + quad * 4;
    const int jg = jloc >> 3, u0 = jloc & 7;   // u0 in {0,4}
    #pragma unroll
    for (int nt = 0; nt < 4; ++nt) {
        const int gnt = ch * 4 + nt;
        ushort4 hv;
        hv.x = h2u((_Float16)acc[nt][0]);
        hv.y = h2u((_Float16)acc[nt][1]);
        hv.z = h2u((_Float16)acc[nt][2]);
        hv.w = h2u((_Float16)acc[nt][3]);
        *reinterpret_cast<ushort4*>(&hF[(size_t)b * 262144 + gnt * 32768 + jg * 128 + nl * 8 + u0]) = hv;
    }

    // ---- s_src / s_dst partials over this wave's 64 cols ----
    float as[4], ad[4];
    #pragma unroll
    for (int nt = 0; nt < 4; ++nt) {
        const int col = ch * 64 + nt * 16 + nl;
        as[nt] = a_src[col];
        ad[nt] = a_dst[col];
    }
    #pragma unroll
    for (int r = 0; r < 4; ++r) {
        float sp = acc[0][r] * as[0] + acc[1][r] * as[1] + acc[2][r] * as[2] + acc[3][r] * as[3];
        float dp = acc[0][r] * ad[0] + acc[1][r] * ad[1] + acc[2][r] * ad[2] + acc[3][r] * ad[3];
        #pragma unroll
        for (int off = 8; off >= 1; off >>= 1) {
            sp += __shfl_xor(sp, off, 16);
            dp += __shfl_xor(dp, off, 16);
        }
        if (nl == 0) {
            sred[ch][mt * 16 + quad * 4 + r] = sp;
            dred[ch][mt * 16 + quad * 4 + r] = dp;
        }
    }
    __syncthreads();
    if (t < 64) {
        const float sp = sred[0][t] + sred[1][t];
        const float dp = dred[0][t] + dred[1][t];
        const int row = row0 + t;
        Sg[row]  = __expf(sp - 2.f);
        S2g[row] = __expf(0.2f * sp - 2.f);
        Eg[row]  = __expf(dp - 2.f);
        E2g[row] = __expf(0.2f * dp - 2.f);
    }
}

// ---------------------------------------------------------------------------
// k_attn: p = mask ? max(Ei*Ej, E2i*E2j) : 0  (= exp(lrelu(si+sj) - 4))
// fp16 hi/lo p through double-buffered LDS -> f16 MFMA against single-plane h.
// grid (32, 8) x 512: block = 64 rows x 128 cols, 32 tiles of 64 j.
// p-gen thread quantum: 2 rows x 4 j.
// ---------------------------------------------------------------------------
__global__ __launch_bounds__(512) void k_attn(const unsigned short* __restrict__ hF,
                                              const unsigned* __restrict__ amT,
                                              const float* __restrict__ Eg,
                                              const float* __restrict__ E2g,
                                              const float* __restrict__ Sg,
                                              const float* __restrict__ S2g,
                                              float* __restrict__ out) {
    __shared__ float E_l[NN];                  // 8 KB
    __shared__ float E2_l[NN];                 // 8 KB
    __shared__ unsigned am_l[64 * 64];         // 16 KB  [jw][row]
    __shared__ unsigned short pA_hi[2][64 * 72]; // 18 KB  A-frag rows, stride 72
    __shared__ unsigned short pA_lo[2][64 * 72]; // 18 KB
    __shared__ float l_s[64];

    const int t = threadIdx.x;
    const int b = blockIdx.y;
    const int i0 = blockIdx.x * 64;

    // ---- stage E/E2 row, transposed mask ----
    *reinterpret_cast<float4*>(&E_l[t * 4])  = *reinterpret_cast<const float4*>(&Eg[(size_t)b * NN + t * 4]);
    *reinterpret_cast<float4*>(&E2_l[t * 4]) = *reinterpret_cast<const float4*>(&E2g[(size_t)b * NN + t * 4]);
    #pragma unroll
    for (int k = 0; k < 8; ++k) {
        const int idx = k * 512 + t;
        am_l[idx] = amT[(size_t)(idx >> 6) * NN + i0 + (idx & 63)];
    }
    __syncthreads();

    // ---- p-gen ids: thread = rows {2rp, 2rp+1} x 4 j ----
    const int rp = t >> 4, jw4 = t & 15;
    const int ra = rp * 2, rb = ra + 1;
    const float2 eia = make_float2(Sg[(size_t)b * NN + i0 + ra], S2g[(size_t)b * NN + i0 + ra]);
    const float2 eib = make_float2(Sg[(size_t)b * NN + i0 + rb], S2g[(size_t)b * NN + i0 + rb]);
    const int bitb = (jw4 & 7) * 4;
    const int pwo = ra * 72 + jw4 * 4;

    // ---- MFMA ids: wave = 16 rows x 64 cols ----
    const int w = t >> 6, lane = t & 63;
    const int mt = w >> 1, ch = w & 1;
    const int nl = lane & 15, quad = lane >> 4;
    const unsigned short* __restrict__ hFb = hF + (size_t)b * 262144;
    int bofs[4];
    #pragma unroll
    for (int nt = 0; nt < 4; ++nt)
        bofs[nt] = (ch * 4 + nt) * 32768 + quad * 128 + nl * 8;
    const int aofs = (mt * 16 + nl) * 72 + quad * 8;

    f32x4 acc[4] = {{0.f,0.f,0.f,0.f},{0.f,0.f,0.f,0.f},{0.f,0.f,0.f,0.f},{0.f,0.f,0.f,0.f}};
    float la = 0.f, lb = 0.f;

    for (int tt = 0; tt < 32; ++tt) {
        const int jt = tt * 64;
        const int buf = tt & 1;
        const int jofs = jt * 16;

        // B-frag loads (global fp16 plane; consumed after barrier)
        half8 bfr[4][2];
        #pragma unroll
        for (int nt = 0; nt < 4; ++nt) {
            bfr[nt][0] = *reinterpret_cast<const half8*>(hFb + bofs[nt] + jofs);
            bfr[nt][1] = *reinterpret_cast<const half8*>(hFb + bofs[nt] + jofs + 512);
        }

        // ---- p-gen: 2 rows x 4 j ----
        {
            const int jb = jt + jw4 * 4;
            const float4 ej4  = *reinterpret_cast<const float4*>(&E_l[jb]);
            const float4 e2j4 = *reinterpret_cast<const float4*>(&E2_l[jb]);
            const uint2 mw = *reinterpret_cast<const uint2*>(&am_l[(tt * 2 + (jw4 >> 3)) * 64 + ra]);
            const float ejA[4]  = {ej4.x, ej4.y, ej4.z, ej4.w};
            const float e2jA[4] = {e2j4.x, e2j4.y, e2j4.z, e2j4.w};
            float pa[4], pb[4];
            #pragma unroll
            for (int jj = 0; jj < 4; ++jj) {
                const float ua = fmaxf(eia.x * ejA[jj], eia.y * e2jA[jj]);
                const float ub = fmaxf(eib.x * ejA[jj], eib.y * e2jA[jj]);
                pa[jj] = ((mw.x >> (bitb + jj)) & 1u) ? ua : 0.f;
                pb[jj] = ((mw.y >> (bitb + jj)) & 1u) ? ub : 0.f;
                la += pa[jj];
                lb += pb[jj];
            }
            ushort4 hv, lv;
            h_split(pa[0], hv.x, lv.x);
            h_split(pa[1], hv.y, lv.y);
            h_split(pa[2], hv.z, lv.z);
            h_split(pa[3], hv.w, lv.w);
            *reinterpret_cast<ushort4*>(&pA_hi[buf][pwo]) = hv;
            *reinterpret_cast<ushort4*>(&pA_lo[buf][pwo]) = lv;
            h_split(pb[0], hv.x, lv.x);
            h_split(pb[1], hv.y, lv.y);
            h_split(pb[2], hv.z, lv.z);
            h_split(pb[3], hv.w, lv.w);
            *reinterpret_cast<ushort4*>(&pA_hi[buf][pwo + 72]) = hv;
            *reinterpret_cast<ushort4*>(&pA_lo[buf][pwo + 72]) = lv;
        }

        __syncthreads();

        // ---- A-frags + MFMA (2 k-halves x hi/lo) ----
        const half8 ah0 = *reinterpret_cast<const half8*>(&pA_hi[buf][aofs]);
        const half8 ah1 = *reinterpret_cast<const half8*>(&pA_hi[buf][aofs + 32]);
        const half8 al0 = *reinterpret_cast<const half8*>(&pA_lo[buf][aofs]);
        const half8 al1 = *reinterpret_cast<const half8*>(&pA_lo[buf][aofs + 32]);
        #pragma unroll
        for (int nt = 0; nt < 4; ++nt) {
            acc[nt] = __builtin_amdgcn_mfma_f32_16x16x32_f16(ah0, bfr[nt][0], acc[nt], 0, 0, 0);
            acc[nt] = __builtin_amdgcn_mfma_f32_16x16x32_f16(al0, bfr[nt][0], acc[nt], 0, 0, 0);
            acc[nt] = __builtin_amdgcn_mfma_f32_16x16x32_f16(ah1, bfr[nt][1], acc[nt], 0, 0, 0);
            acc[nt] = __builtin_amdgcn_mfma_f32_16x16x32_f16(al1, bfr[nt][1], acc[nt], 0, 0, 0);
        }
    }

    // ---- row sums ----
    #pragma unroll
    for (int off = 8; off >= 1; off >>= 1) {
        la += __shfl_xor(la, off, 16);
        lb += __shfl_xor(lb, off, 16);
    }
    if (jw4 == 0) {
        l_s[ra] = la;
        l_s[rb] = lb;
    }
    __syncthreads();
    if (t < 64) {
        const float l = l_s[t];
        l_s[t] = (l > 0.f) ? 1.f / l : 0.f;
    }
    __syncthreads();

    // ---- epilogue: C/D layout col=lane&15, row=quad*4+reg ----
    const int col0 = ch * 64 + nl;
    #pragma unroll
    for (int nt = 0; nt < 4; ++nt) {
        #pragma unroll
        for (int r = 0; r < 4; ++r) {
            const int lrow = mt * 16 + quad * 4 + r;
            out[((size_t)b * NN + i0 + lrow) * FF + col0 + nt * 16] = acc[nt][r] * l_s[lrow];
        }
    }
}

extern "C" void kernel_launch(void* const* d_in, const int* in_sizes, int n_in,
                              void* d_out, int out_size, void* d_ws, size_t ws_size,
                              hipStream_t stream) {
    const float* x     = (const float*)d_in[0];
    const int*   adj   = (const int*)d_in[1];
    const float* W     = (const float*)d_in[2];
    const float* a_src = (const float*)d_in[3];
    const float* a_dst = (const float*)d_in[4];
    float* out = (float*)d_out;

    unsigned short* hF    = (unsigned short*)d_ws;        // 4 MB
    unsigned short* Wf_hi = hF + 2097152;                 // 32 KB
    unsigned short* Wf_lo = Wf_hi + 16384;                // 32 KB
    float* Eg  = (float*)(Wf_lo + 16384);                 // 64 KB
    float* E2g = Eg + 16384;                              // 64 KB
    float* Sg  = E2g + 16384;                             // 64 KB
    float* S2g = Sg + 16384;                              // 64 KB
    unsigned* amT = (unsigned*)(S2g + 16384);             // 512 KB

    k_prep<<<129, 512, 0, stream>>>(adj, W, Wf_hi, Wf_lo, amT);
    k_h<<<256, 512, 0, stream>>>(x, Wf_hi, Wf_lo, a_src, a_dst, hF, Eg, E2g, Sg, S2g);
    k_attn<<<dim3(NN / 64, BATCH), 512, 0, stream>>>(hF, amT, Eg, E2g, Sg, S2g, out);
}

// Round 6
// 124.214 us; speedup vs baseline: 2.7516x; 1.0587x over previous
//
#include <hip/hip_runtime.h>
#include <math.h>

#define BATCH 8
#define NN 2048
#define FF 128

typedef __attribute__((ext_vector_type(4))) float f32x4;
typedef _Float16 half8 __attribute__((ext_vector_type(8)));

__device__ __forceinline__ unsigned short h2u(_Float16 h) {
    return __builtin_bit_cast(unsigned short, h);
}

__device__ __forceinline__ void h_split(float f, unsigned short& hi, unsigned short& lo) {
    const _Float16 hh = (_Float16)f;
    hi = h2u(hh);
    lo = h2u((_Float16)(f - (float)hh));
}

// ---------------------------------------------------------------------------
// k_prep: blocks 0..127: adj -> transposed bitmask amT[jw(64)][i(2048)] via
//         ballot, seg-loop unrolled x16 so loads pipeline (was latency-serial).
//         block 128: W -> fp16 hi/lo B-fragment planes Wf[ks][nt][lane][j]
// ---------------------------------------------------------------------------
__global__ __launch_bounds__(512) void k_prep(const int* __restrict__ adj,
                                              const float* __restrict__ W,
                                              unsigned short* __restrict__ Wf_hi,
                                              unsigned short* __restrict__ Wf_lo,
                                              unsigned* __restrict__ amT) {
    const int t = threadIdx.x;
    if (blockIdx.x == 128) {
        #pragma unroll 4
        for (int e = 0; e < 32; ++e) {
            const int fi = e * 512 + t;
            const int j = fi & 7, lane = (fi >> 3) & 63, nt = (fi >> 9) & 7, ks = fi >> 12;
            const int k = ks * 32 + (lane >> 4) * 8 + j;
            const int col = nt * 16 + (lane & 15);
            unsigned short hh, hl;
            h_split(W[k * FF + col], hh, hl);
            Wf_hi[fi] = hh;
            Wf_lo[fi] = hl;
        }
    } else {
        const int w = t >> 6, lane = t & 63;
        const int row = blockIdx.x * 16 + w * 2;
        #pragma unroll
        for (int rr = 0; rr < 2; ++rr) {
            const int* __restrict__ ar = adj + (size_t)(row + rr) * NN;
            #pragma unroll 16
            for (int seg = 0; seg < 32; ++seg) {
                const unsigned long long m = __ballot(ar[seg * 64 + lane] != 0);
                if (lane == 0)  amT[(size_t)(seg * 2) * NN + row + rr] = (unsigned)m;
                if (lane == 32) amT[(size_t)(seg * 2 + 1) * NN + row + rr] = (unsigned)(m >> 32);
            }
        }
    }
}

// ---------------------------------------------------------------------------
// k_h: h = x@W via fp16-split MFMA (xh*Wh + xl*Wh + xh*Wl), h emitted as ONE
// fp16 plane in B-frag layout; epilogue computes the factored exponentials.
// grid 256 x 512: block = 64 rows x 128 cols; wave = 16 rows x 64 cols.
// ---------------------------------------------------------------------------
__global__ __launch_bounds__(512) void k_h(const float* __restrict__ x,
                                           const unsigned short* __restrict__ Wf_hi,
                                           const unsigned short* __restrict__ Wf_lo,
                                           const float* __restrict__ a_src,
                                           const float* __restrict__ a_dst,
                                           unsigned short* __restrict__ hF,
                                           float* __restrict__ Eg,  float* __restrict__ E2g,
                                           float* __restrict__ Sg,  float* __restrict__ S2g) {
    __shared__ float sred[2][64];
    __shared__ float dred[2][64];

    const int t = threadIdx.x;
    const int w = t >> 6, lane = t & 63;
    const int mt = w >> 1, ch = w & 1;
    const int nl = lane & 15, quad = lane >> 4;
    const int row0 = blockIdx.x * 64;
    const int b = row0 >> 11, jloc0 = row0 & 2047;
    const int gr = row0 + mt * 16 + nl;

    f32x4 acc[4] = {{0.f,0.f,0.f,0.f},{0.f,0.f,0.f,0.f},{0.f,0.f,0.f,0.f},{0.f,0.f,0.f,0.f}};

    #pragma unroll
    for (int ks = 0; ks < 4; ++ks) {
        const float4 xa = *reinterpret_cast<const float4*>(&x[(size_t)gr * FF + ks * 32 + quad * 8]);
        const float4 xb = *reinterpret_cast<const float4*>(&x[(size_t)gr * FF + ks * 32 + quad * 8 + 4]);
        const float xv[8] = {xa.x, xa.y, xa.z, xa.w, xb.x, xb.y, xb.z, xb.w};
        half8 ah, al;
        #pragma unroll
        for (int i = 0; i < 8; ++i) {
            const _Float16 hh = (_Float16)xv[i];
            ah[i] = hh;
            al[i] = (_Float16)(xv[i] - (float)hh);
        }
        #pragma unroll
        for (int nt = 0; nt < 4; ++nt) {
            const int gnt = ch * 4 + nt;
            const int bo = ((ks * 8 + gnt) * 64 + lane) * 8;
            const half8 bh = *reinterpret_cast<const half8*>(&Wf_hi[bo]);
            const half8 bl = *reinterpret_cast<const half8*>(&Wf_lo[bo]);
            acc[nt] = __builtin_amdgcn_mfma_f32_16x16x32_f16(ah, bh, acc[nt], 0, 0, 0);
            acc[nt] = __builtin_amdgcn_mfma_f32_16x16x32_f16(al, bh, acc[nt], 0, 0, 0);
            acc[nt] = __builtin_amdgcn_mfma_f32_16x16x32_f16(ah, bl, acc[nt], 0, 0, 0);
        }
    }

    // ---- h store: fp16 plane, B-frag layout [b][gnt][jg][n][u] ----
    const int jloc = jloc0 + mt * 16 + quad * 4;
    const int jg = jloc >> 3, u0 = jloc & 7;
    #pragma unroll
    for (int nt = 0; nt < 4; ++nt) {
        const int gnt = ch * 4 + nt;
        ushort4 hv;
        hv.x = h2u((_Float16)acc[nt][0]);
        hv.y = h2u((_Float16)acc[nt][1]);
        hv.z = h2u((_Float16)acc[nt][2]);
        hv.w = h2u((_Float16)acc[nt][3]);
        *reinterpret_cast<ushort4*>(&hF[(size_t)b * 262144 + gnt * 32768 + jg * 128 + nl * 8 + u0]) = hv;
    }

    // ---- s_src / s_dst partials over this wave's 64 cols ----
    float as[4], ad[4];
    #pragma unroll
    for (int nt = 0; nt < 4; ++nt) {
        const int col = ch * 64 + nt * 16 + nl;
        as[nt] = a_src[col];
        ad[nt] = a_dst[col];
    }
    #pragma unroll
    for (int r = 0; r < 4; ++r) {
        float sp = acc[0][r] * as[0] + acc[1][r] * as[1] + acc[2][r] * as[2] + acc[3][r] * as[3];
        float dp = acc[0][r] * ad[0] + acc[1][r] * ad[1] + acc[2][r] * ad[2] + acc[3][r] * ad[3];
        #pragma unroll
        for (int off = 8; off >= 1; off >>= 1) {
            sp += __shfl_xor(sp, off, 16);
            dp += __shfl_xor(dp, off, 16);
        }
        if (nl == 0) {
            sred[ch][mt * 16 + quad * 4 + r] = sp;
            dred[ch][mt * 16 + quad * 4 + r] = dp;
        }
    }
    __syncthreads();
    if (t < 64) {
        const float sp = sred[0][t] + sred[1][t];
        const float dp = dred[0][t] + dred[1][t];
        const int row = row0 + t;
        Sg[row]  = __expf(sp - 2.f);
        S2g[row] = __expf(0.2f * sp - 2.f);
        Eg[row]  = __expf(dp - 2.f);
        E2g[row] = __expf(0.2f * dp - 2.f);
    }
}

// ---------------------------------------------------------------------------
// k_attn: p = mask ? max(Si*Ej, S2i*E2j) : 0  (= exp(lrelu(si+sj) - 4))
// Single fp16 p plane -> f16 MFMA vs single-plane h. Row sums via MFMA
// against ones-B (normalizes the QUANTIZED p exactly; no cross-thread l
// reduction). grid (32,8) x 512: block = 64 rows x 128 cols; wave = 2 mtiles
// x 2 ntiles (B dup 2x, A dup 2x). 32 j-tiles of 64, double-buffered pA,
// one barrier per tile.
// ---------------------------------------------------------------------------
__global__ __launch_bounds__(512, 2) void k_attn(const unsigned short* __restrict__ hF,
                                                 const unsigned* __restrict__ amT,
                                                 const float* __restrict__ Eg,
                                                 const float* __restrict__ E2g,
                                                 const float* __restrict__ Sg,
                                                 const float* __restrict__ S2g,
                                                 float* __restrict__ out) {
    __shared__ float E_l[NN];                    // 8 KB
    __shared__ float E2_l[NN];                   // 8 KB
    __shared__ unsigned am_l[64 * 64];           // 16 KB  [jw][row]
    __shared__ unsigned short pA[2][64 * 72];    // 18 KB  p rows, stride 72

    const int t = threadIdx.x;
    const int b = blockIdx.y;
    const int i0 = blockIdx.x * 64;

    *reinterpret_cast<float4*>(&E_l[t * 4])  = *reinterpret_cast<const float4*>(&Eg[(size_t)b * NN + t * 4]);
    *reinterpret_cast<float4*>(&E2_l[t * 4]) = *reinterpret_cast<const float4*>(&E2g[(size_t)b * NN + t * 4]);
    #pragma unroll
    for (int k = 0; k < 8; ++k) {
        const int idx = k * 512 + t;
        am_l[idx] = amT[(size_t)(idx >> 6) * NN + i0 + (idx & 63)];
    }
    __syncthreads();

    // ---- p-gen ids: thread = rows {2rp, 2rp+1} x 4 j ----
    const int rp = t >> 4, jw4 = t & 15;
    const int ra = rp * 2, rb = ra + 1;
    const float Sa  = Sg[(size_t)b * NN + i0 + ra];
    const float S2a = S2g[(size_t)b * NN + i0 + ra];
    const float Sb  = Sg[(size_t)b * NN + i0 + rb];
    const float S2b = S2g[(size_t)b * NN + i0 + rb];
    const int bitb = (jw4 & 7) * 4;
    const int pwo = ra * 72 + jw4 * 4;

    // ---- MFMA ids: wave = mtiles {mtp, mtp+2} x ntiles {ntp, ntp+4} ----
    const int w = t >> 6, lane = t & 63;
    const int nl = lane & 15, quad = lane >> 4;
    const int mtp = w & 1, ntp = w >> 1;
    const unsigned short* __restrict__ hFb = hF + (size_t)b * 262144;
    int bofs[2], aofs[2];
    #pragma unroll
    for (int nn = 0; nn < 2; ++nn) bofs[nn] = (ntp + nn * 4) * 32768 + quad * 128 + nl * 8;
    #pragma unroll
    for (int mm = 0; mm < 2; ++mm) aofs[mm] = ((mtp + mm * 2) * 16 + nl) * 72 + quad * 8;

    f32x4 acc[2][2] = {{{0.f,0.f,0.f,0.f},{0.f,0.f,0.f,0.f}},{{0.f,0.f,0.f,0.f},{0.f,0.f,0.f,0.f}}};
    f32x4 lac[2] = {{0.f,0.f,0.f,0.f},{0.f,0.f,0.f,0.f}};
    half8 ones;
    #pragma unroll
    for (int i = 0; i < 8; ++i) ones[i] = (_Float16)1.f;

    for (int tt = 0; tt < 32; ++tt) {
        const int jt = tt * 64;
        const int buf = tt & 1;
        const int jofs = jt * 16;

        // ---- B-frag loads (consumed after barrier) ----
        half8 bfr[2][2];
        #pragma unroll
        for (int nn = 0; nn < 2; ++nn) {
            bfr[nn][0] = *reinterpret_cast<const half8*>(hFb + bofs[nn] + jofs);
            bfr[nn][1] = *reinterpret_cast<const half8*>(hFb + bofs[nn] + jofs + 512);
        }

        // ---- p-gen: 2 rows x 4 j, single fp16 plane ----
        {
            const int jb = jt + jw4 * 4;
            const float4 ej4  = *reinterpret_cast<const float4*>(&E_l[jb]);
            const float4 e2j4 = *reinterpret_cast<const float4*>(&E2_l[jb]);
            const uint2 mw = *reinterpret_cast<const uint2*>(&am_l[(tt * 2 + (jw4 >> 3)) * 64 + ra]);
            const float ejA[4]  = {ej4.x, ej4.y, ej4.z, ej4.w};
            const float e2jA[4] = {e2j4.x, e2j4.y, e2j4.z, e2j4.w};
            ushort4 ha, hb;
            #pragma unroll
            for (int jj = 0; jj < 4; ++jj) {
                const float ua = fmaxf(Sa * ejA[jj], S2a * e2jA[jj]);
                const float ub = fmaxf(Sb * ejA[jj], S2b * e2jA[jj]);
                const float pa = ((mw.x >> (bitb + jj)) & 1u) ? ua : 0.f;
                const float pb = ((mw.y >> (bitb + jj)) & 1u) ? ub : 0.f;
                ((unsigned short*)&ha)[jj] = h2u((_Float16)pa);
                ((unsigned short*)&hb)[jj] = h2u((_Float16)pb);
            }
            *reinterpret_cast<ushort4*>(&pA[buf][pwo]) = ha;
            *reinterpret_cast<ushort4*>(&pA[buf][pwo + 72]) = hb;
        }

        __syncthreads();

        // ---- A-frags + MFMA (2 mtiles x 2 khalves; ones-B gives row sums) ----
        half8 afr[2][2];
        #pragma unroll
        for (int mm = 0; mm < 2; ++mm) {
            afr[mm][0] = *reinterpret_cast<const half8*>(&pA[buf][aofs[mm]]);
            afr[mm][1] = *reinterpret_cast<const half8*>(&pA[buf][aofs[mm] + 32]);
        }
        #pragma unroll
        for (int mm = 0; mm < 2; ++mm) {
            #pragma unroll
            for (int kh = 0; kh < 2; ++kh) {
                lac[mm] = __builtin_amdgcn_mfma_f32_16x16x32_f16(afr[mm][kh], ones, lac[mm], 0, 0, 0);
                acc[mm][0] = __builtin_amdgcn_mfma_f32_16x16x32_f16(afr[mm][kh], bfr[0][kh], acc[mm][0], 0, 0, 0);
                acc[mm][1] = __builtin_amdgcn_mfma_f32_16x16x32_f16(afr[mm][kh], bfr[1][kh], acc[mm][1], 0, 0, 0);
            }
        }
    }

    // ---- epilogue: C/D layout col=lane&15, row=quad*4+reg; l from lac ----
    #pragma unroll
    for (int mm = 0; mm < 2; ++mm) {
        const int row = i0 + (mtp + mm * 2) * 16 + quad * 4;
        #pragma unroll
        for (int r = 0; r < 4; ++r) {
            const float l = lac[mm][r];
            const float inv = (l > 0.f) ? 1.f / l : 0.f;
            #pragma unroll
            for (int nn = 0; nn < 2; ++nn) {
                const int col = (ntp + nn * 4) * 16 + nl;
                out[((size_t)b * NN + row + r) * FF + col] = acc[mm][nn][r] * inv;
            }
        }
    }
}

extern "C" void kernel_launch(void* const* d_in, const int* in_sizes, int n_in,
                              void* d_out, int out_size, void* d_ws, size_t ws_size,
                              hipStream_t stream) {
    const float* x     = (const float*)d_in[0];
    const int*   adj   = (const int*)d_in[1];
    const float* W     = (const float*)d_in[2];
    const float* a_src = (const float*)d_in[3];
    const float* a_dst = (const float*)d_in[4];
    float* out = (float*)d_out;

    unsigned short* hF    = (unsigned short*)d_ws;        // 4 MB
    unsigned short* Wf_hi = hF + 2097152;                 // 32 KB
    unsigned short* Wf_lo = Wf_hi + 16384;                // 32 KB
    float* Eg  = (float*)(Wf_lo + 16384);                 // 64 KB
    float* E2g = Eg + 16384;                              // 64 KB
    float* Sg  = E2g + 16384;                             // 64 KB
    float* S2g = Sg + 16384;                              // 64 KB
    unsigned* amT = (unsigned*)(S2g + 16384);             // 512 KB

    k_prep<<<129, 512, 0, stream>>>(adj, W, Wf_hi, Wf_lo, amT);
    k_h<<<256, 512, 0, stream>>>(x, Wf_hi, Wf_lo, a_src, a_dst, hF, Eg, E2g, Sg, S2g);
    k_attn<<<dim3(NN / 64, BATCH), 512, 0, stream>>>(hF, amT, Eg, E2g, Sg, S2g, out);
}